// Round 1
// baseline (1019.024 us; speedup 1.0000x reference)
//
#include <hip/hip_runtime.h>

#define N_NODES  100000
#define N_EDGES  3200000
#define N_FEAT   512
#define N_GRAPHS 64
#define N_COLS   516   // 512 x-features + 4 layer outputs
#define CHUNK    25    // nodes per wave in the fused x pass

// ---------------------------------------------------------------------------
// Kernel A: fused pass over x.
//  - p0[n] = x[n] . W_neigh0
//  - s0[n] = x[n] . W_self0
//  - out[g, 0:512] += x[n]   (per-graph feature sums; graph_ids sorted ->
//    register accumulate, flush at graph boundary only)
//  - zeroes neigh[] for the first edge pass
// One wave handles CHUNK consecutive nodes; lane l holds features
// [4l,4l+4) and [256+4l, 256+4l+4) of each row (two dense float4 loads).
// ---------------------------------------------------------------------------
__global__ __launch_bounds__(256) void pass_x_kernel(
    const float* __restrict__ x, const int* __restrict__ gid,
    const float* __restrict__ wn, const float* __restrict__ ws,
    float* __restrict__ p0, float* __restrict__ s0,
    float* __restrict__ neigh, float* __restrict__ out)
{
    const int wave = (blockIdx.x * blockDim.x + threadIdx.x) >> 6;
    const int lane = threadIdx.x & 63;
    const int start = wave * CHUNK;
    if (start >= N_NODES) return;
    const int end = (start + CHUNK < N_NODES) ? start + CHUNK : N_NODES;

    // zero the neighbor accumulator for this node range
    for (int n = start + lane; n < end; n += 64) neigh[n] = 0.0f;

    const float4 wna = *(const float4*)(wn + lane * 4);
    const float4 wnb = *(const float4*)(wn + 256 + lane * 4);
    const float4 wsa = *(const float4*)(ws + lane * 4);
    const float4 wsb = *(const float4*)(ws + 256 + lane * 4);

    float a0 = 0.f, a1 = 0.f, a2 = 0.f, a3 = 0.f;
    float c0 = 0.f, c1 = 0.f, c2 = 0.f, c3 = 0.f;
    int cur_g = gid[start];

    for (int n = start; n < end; ++n) {
        const int g = gid[n];   // wave-uniform (all lanes same n)
        if (g != cur_g) {
            float* o = out + (size_t)cur_g * N_COLS;
            atomicAdd(o + lane * 4 + 0, a0);
            atomicAdd(o + lane * 4 + 1, a1);
            atomicAdd(o + lane * 4 + 2, a2);
            atomicAdd(o + lane * 4 + 3, a3);
            atomicAdd(o + 256 + lane * 4 + 0, c0);
            atomicAdd(o + 256 + lane * 4 + 1, c1);
            atomicAdd(o + 256 + lane * 4 + 2, c2);
            atomicAdd(o + 256 + lane * 4 + 3, c3);
            a0 = a1 = a2 = a3 = c0 = c1 = c2 = c3 = 0.f;
            cur_g = g;
        }
        const float* row = x + (size_t)n * N_FEAT;
        const float4 xa = *(const float4*)(row + lane * 4);
        const float4 xb = *(const float4*)(row + 256 + lane * 4);

        a0 += xa.x; a1 += xa.y; a2 += xa.z; a3 += xa.w;
        c0 += xb.x; c1 += xb.y; c2 += xb.z; c3 += xb.w;

        float dn = xa.x * wna.x + xa.y * wna.y + xa.z * wna.z + xa.w * wna.w
                 + xb.x * wnb.x + xb.y * wnb.y + xb.z * wnb.z + xb.w * wnb.w;
        float dv = xa.x * wsa.x + xa.y * wsa.y + xa.z * wsa.z + xa.w * wsa.w
                 + xb.x * wsb.x + xb.y * wsb.y + xb.z * wsb.z + xb.w * wsb.w;

        #pragma unroll
        for (int off = 32; off > 0; off >>= 1) {
            dn += __shfl_down(dn, off);
            dv += __shfl_down(dv, off);
        }
        if (lane == 0) { p0[n] = dn; s0[n] = dv; }
    }
    // final flush
    float* o = out + (size_t)cur_g * N_COLS;
    atomicAdd(o + lane * 4 + 0, a0);
    atomicAdd(o + lane * 4 + 1, a1);
    atomicAdd(o + lane * 4 + 2, a2);
    atomicAdd(o + lane * 4 + 3, a3);
    atomicAdd(o + 256 + lane * 4 + 0, c0);
    atomicAdd(o + 256 + lane * 4 + 1, c1);
    atomicAdd(o + 256 + lane * 4 + 2, c2);
    atomicAdd(o + 256 + lane * 4 + 3, c3);
}

// ---------------------------------------------------------------------------
// Kernel B: edge scatter — neigh[dst] += p[src], 4 edges per thread.
// N_EDGES % 4 == 0.
// ---------------------------------------------------------------------------
__global__ __launch_bounds__(256) void edge_scatter_kernel(
    const int4* __restrict__ src4, const int4* __restrict__ dst4,
    const float* __restrict__ p, float* __restrict__ neigh)
{
    const int i = blockIdx.x * blockDim.x + threadIdx.x;
    if (i >= N_EDGES / 4) return;
    const int4 s = src4[i];
    const int4 d = dst4[i];
    const float p0 = p[s.x], p1 = p[s.y], p2 = p[s.z], p3 = p[s.w];
    atomicAdd(&neigh[d.x], p0);
    atomicAdd(&neigh[d.y], p1);
    atomicAdd(&neigh[d.z], p2);
    atomicAdd(&neigh[d.w], p3);
}

// ---------------------------------------------------------------------------
// Kernel C: node update for one layer.
//   h = relu(neigh[n] + bias + self_w * self_in[n])     (self_w=1 if null)
//   h_out[n] = h;  p_next[n] = h * wn_next (if non-null);  neigh[n] = 0
//   out[g, col] += h  (wave-segmented reduce: one atomic per uniform wave)
// ---------------------------------------------------------------------------
__global__ __launch_bounds__(256) void node_update_kernel(
    const float* __restrict__ neigh_in, const float* __restrict__ self_in,
    const float* __restrict__ wself_p, const float* __restrict__ bias_p,
    const float* __restrict__ wnext_p,
    float* __restrict__ h_out, float* __restrict__ p_next,
    float* __restrict__ neigh_zero,
    const int* __restrict__ gid, float* __restrict__ out, int col)
{
    const int n = blockIdx.x * blockDim.x + threadIdx.x;
    const bool valid = (n < N_NODES);
    float h = 0.f;
    int g = 0;
    if (valid) {
        const float sw = wself_p ? *wself_p : 1.0f;
        const float v = neigh_in[n] + *bias_p + sw * self_in[n];
        h = v > 0.f ? v : 0.f;
        h_out[n] = h;
        if (wnext_p) p_next[n] = h * (*wnext_p);
        neigh_zero[n] = 0.0f;
        g = gid[n];
    }
    // per-graph sum of h into out[g*N_COLS + col]
    const int g0 = __shfl(g, 0);     // valid lanes form a prefix of the wave
    if (__all(valid && g == g0)) {
        float s = h;
        #pragma unroll
        for (int off = 32; off > 0; off >>= 1) s += __shfl_down(s, off);
        if ((threadIdx.x & 63) == 0)
            atomicAdd(&out[(size_t)g0 * N_COLS + col], s);
    } else if (valid) {
        atomicAdd(&out[(size_t)g * N_COLS + col], h);
    }
}

extern "C" void kernel_launch(void* const* d_in, const int* in_sizes, int n_in,
                              void* d_out, int out_size, void* d_ws, size_t ws_size,
                              hipStream_t stream)
{
    (void)in_sizes; (void)n_in; (void)out_size; (void)ws_size;

    const float* x    = (const float*)d_in[0];
    const int*   esrc = (const int*)d_in[1];
    const int*   edst = (const int*)d_in[2];
    const int*   gid  = (const int*)d_in[3];
    const float* Wn0  = (const float*)d_in[4];
    const float* Ws0  = (const float*)d_in[5];
    const float* b0p  = (const float*)d_in[6];
    const float* Wnr  = (const float*)d_in[7];   // 3 scalars
    const float* Wsr  = (const float*)d_in[8];   // 3 scalars
    const float* brp  = (const float*)d_in[9];   // 3 scalars
    float* out = (float*)d_out;

    float* bufP = (float*)d_ws;          // projected values (scatter source)
    float* bufS = bufP + N_NODES;        // x . W_self0
    float* bufN = bufS + N_NODES;        // neighbor accumulator
    float* bufH = bufN + N_NODES;        // current h

    hipMemsetAsync(d_out, 0, (size_t)N_GRAPHS * N_COLS * sizeof(float), stream);

    const int wavesA  = (N_NODES + CHUNK - 1) / CHUNK;   // 4000 waves
    const int blocksA = (wavesA + 3) / 4;                // 4 waves / block
    pass_x_kernel<<<blocksA, 256, 0, stream>>>(x, gid, Wn0, Ws0,
                                               bufP, bufS, bufN, out);

    const int blocksB = (N_EDGES / 4 + 255) / 256;       // 3125
    const int blocksC = (N_NODES + 255) / 256;           // 391

    // Layer 0: h1 = relu(scatter(p0) + b0 + s0); p_next = h1 * Wnr[0]
    edge_scatter_kernel<<<blocksB, 256, 0, stream>>>(
        (const int4*)esrc, (const int4*)edst, bufP, bufN);
    node_update_kernel<<<blocksC, 256, 0, stream>>>(
        bufN, bufS, nullptr, b0p, Wnr + 0, bufH, bufP, bufN, gid, out, 512);

    // Layer 1
    edge_scatter_kernel<<<blocksB, 256, 0, stream>>>(
        (const int4*)esrc, (const int4*)edst, bufP, bufN);
    node_update_kernel<<<blocksC, 256, 0, stream>>>(
        bufN, bufH, Wsr + 0, brp + 0, Wnr + 1, bufH, bufP, bufN, gid, out, 513);

    // Layer 2
    edge_scatter_kernel<<<blocksB, 256, 0, stream>>>(
        (const int4*)esrc, (const int4*)edst, bufP, bufN);
    node_update_kernel<<<blocksC, 256, 0, stream>>>(
        bufN, bufH, Wsr + 1, brp + 1, Wnr + 2, bufH, bufP, bufN, gid, out, 514);

    // Layer 3 (no next projection)
    edge_scatter_kernel<<<blocksB, 256, 0, stream>>>(
        (const int4*)esrc, (const int4*)edst, bufP, bufN);
    node_update_kernel<<<blocksC, 256, 0, stream>>>(
        bufN, bufH, Wsr + 2, brp + 2, nullptr, bufH, bufP, bufN, gid, out, 515);
}

// Round 2
// 525.586 us; speedup vs baseline: 1.9388x; 1.9388x over previous
//
#include <hip/hip_runtime.h>

#define N_NODES  100000
#define N_EDGES  3200000
#define N_FEAT   512
#define N_GRAPHS 64
#define N_COLS   516
#define NBINS    1563            // ceil(N_NODES / 64), 64 nodes per bin
#define B1       256             // blocks for hist/reorder
#define EPB      (N_EDGES / B1)  // 12500 edges per block chunk
#define CCHUNK   16              // colsum row-chunks per graph
#define SRC_MASK 0x1FFFF         // 17 bits for src id (< 131072)

// ---------------------------------------------------------------------------
// find graph start offsets (graph_ids sorted). starts[g] = first node of g,
// starts[64] = N_NODES; empty graphs get start = next graph's start.
// ---------------------------------------------------------------------------
__global__ __launch_bounds__(256) void find_starts_kernel(
    const int* __restrict__ gid, int* __restrict__ starts)
{
    const int n = blockIdx.x * blockDim.x + threadIdx.x;
    if (n >= N_NODES) return;
    const int g = gid[n];
    const int gp = (n == 0) ? -1 : gid[n - 1];
    for (int q = gp + 1; q <= g; ++q) starts[q] = n;
    if (n == N_NODES - 1)
        for (int q = g + 1; q <= N_GRAPHS; ++q) starts[q] = N_NODES;
}

// ---------------------------------------------------------------------------
// GEMV: p0[n] = x[n].Wn, s0[n] = x[n].Ws. Wave per row, lane covers 8 cols.
// Branch-free inner loop -> loads pipeline across iterations.
// ---------------------------------------------------------------------------
__global__ __launch_bounds__(256) void dots_kernel(
    const float* __restrict__ x, const float* __restrict__ wn,
    const float* __restrict__ ws, float* __restrict__ p0, float* __restrict__ s0)
{
    const int lane = threadIdx.x & 63;
    const int wid = (blockIdx.x * blockDim.x + threadIdx.x) >> 6;
    const int nwaves = (gridDim.x * blockDim.x) >> 6;

    const float4 wna = *(const float4*)(wn + lane * 8);
    const float4 wnb = *(const float4*)(wn + lane * 8 + 4);
    const float4 wsa = *(const float4*)(ws + lane * 8);
    const float4 wsb = *(const float4*)(ws + lane * 8 + 4);

    for (int n = wid; n < N_NODES; n += nwaves) {
        const float* row = x + (size_t)n * N_FEAT;
        const float4 xa = *(const float4*)(row + lane * 8);
        const float4 xb = *(const float4*)(row + lane * 8 + 4);
        float dn = xa.x*wna.x + xa.y*wna.y + xa.z*wna.z + xa.w*wna.w
                 + xb.x*wnb.x + xb.y*wnb.y + xb.z*wnb.z + xb.w*wnb.w;
        float dv = xa.x*wsa.x + xa.y*wsa.y + xa.z*wsa.z + xa.w*wsa.w
                 + xb.x*wsb.x + xb.y*wsb.y + xb.z*wsb.z + xb.w*wsb.w;
        #pragma unroll
        for (int off = 32; off > 0; off >>= 1) {
            dn += __shfl_down(dn, off);
            dv += __shfl_down(dv, off);
        }
        if (lane == 0) { p0[n] = dn; s0[n] = dv; }
    }
}

// ---------------------------------------------------------------------------
// Per-graph column sums of x, fully coalesced, no atomics.
// grid = (CCHUNK, N_GRAPHS). Block = 256 = 128 col-chunks x 2 row-walkers.
// Writes partial[(chunk*2+walker)][g][512]; always writes (zeros if no rows).
// ---------------------------------------------------------------------------
__global__ __launch_bounds__(256) void colsum_kernel(
    const float* __restrict__ x, const int* __restrict__ starts,
    float* __restrict__ partial)
{
    const int g = blockIdx.y, chunk = blockIdx.x;
    const int walker = threadIdx.x >> 7;        // 0/1
    const int t = threadIdx.x & 127;            // col-chunk (float4)
    const int s = starts[g], e = starts[g + 1];
    const int len = e - s;
    const int rs = s + (int)(((long long)len * chunk) / CCHUNK);
    const int re = s + (int)(((long long)len * (chunk + 1)) / CCHUNK);

    float4 acc = make_float4(0.f, 0.f, 0.f, 0.f);
    for (int r = rs + walker; r < re; r += 2) {
        const float4 v = *(const float4*)(x + (size_t)r * N_FEAT + t * 4);
        acc.x += v.x; acc.y += v.y; acc.z += v.z; acc.w += v.w;
    }
    const int slot = chunk * 2 + walker;        // 0..31
    *(float4*)(partial + ((size_t)slot * N_GRAPHS + g) * N_FEAT + t * 4) = acc;
}

__global__ __launch_bounds__(512) void reduce_partial_kernel(
    const float* __restrict__ partial, float* __restrict__ out)
{
    const int g = blockIdx.x, c = threadIdx.x;  // 512 cols
    float s = 0.f;
    for (int k = 0; k < 2 * CCHUNK; ++k)
        s += partial[((size_t)k * N_GRAPHS + g) * N_FEAT + c];
    out[(size_t)g * N_COLS + c] = s;
}

// ---------------------------------------------------------------------------
// Sort pipeline: counting sort of edges by dst bin (dst >> 6).
// ---------------------------------------------------------------------------
__global__ __launch_bounds__(256) void hist_kernel(
    const int* __restrict__ edst, int* __restrict__ histG)
{
    __shared__ int lh[NBINS];
    const int b = blockIdx.x, tid = threadIdx.x;
    for (int i = tid; i < NBINS; i += 256) lh[i] = 0;
    __syncthreads();
    const int e0 = b * EPB;
    for (int e = e0 + tid; e < e0 + EPB; e += 256)
        atomicAdd(&lh[edst[e] >> 6], 1);
    __syncthreads();
    for (int i = tid; i < NBINS; i += 256) histG[i * B1 + b] = lh[i];
}

// per-bin exclusive scan across the B1 blocks; also bin totals
__global__ __launch_bounds__(256) void colscan_kernel(
    const int* __restrict__ histG, int* __restrict__ colscanG,
    int* __restrict__ totalG)
{
    __shared__ int sc[256];
    const int bin = blockIdx.x, t = threadIdx.x;
    const int v = histG[bin * B1 + t];
    sc[t] = v;
    __syncthreads();
    for (int off = 1; off < 256; off <<= 1) {
        const int a = (t >= off) ? sc[t - off] : 0;
        __syncthreads();
        sc[t] += a;
        __syncthreads();
    }
    colscanG[bin * B1 + t] = sc[t] - v;
    if (t == 255) totalG[bin] = sc[255];
}

// single-block exclusive scan of bin totals -> binstart[NBINS+1]
__global__ __launch_bounds__(256) void scan2_kernel(
    const int* __restrict__ totalG, int* __restrict__ binstart)
{
    __shared__ int sc[256];
    const int t = threadIdx.x;
    const int CH = 7;                           // 256*7 >= NBINS
    int loc[CH];
    int s = 0;
    for (int i = 0; i < CH; ++i) {
        const int bin = t * CH + i;
        const int v = (bin < NBINS) ? totalG[bin] : 0;
        loc[i] = s; s += v;
    }
    const int my = s;
    sc[t] = my;
    __syncthreads();
    for (int off = 1; off < 256; off <<= 1) {
        const int a = (t >= off) ? sc[t - off] : 0;
        __syncthreads();
        sc[t] += a;
        __syncthreads();
    }
    const int texcl = sc[t] - my;
    for (int i = 0; i < CH; ++i) {
        const int bin = t * CH + i;
        if (bin < NBINS) binstart[bin] = texcl + loc[i];
    }
    if (t == 255) binstart[NBINS] = sc[255];    // == N_EDGES
}

// place edges: sorted[p] = src | ((dst & 63) << 17), grouped by bin
__global__ __launch_bounds__(256) void reorder_kernel(
    const int* __restrict__ esrc, const int* __restrict__ edst,
    const int* __restrict__ binstart, const int* __restrict__ colscanG,
    int* __restrict__ sorted)
{
    __shared__ int offs[NBINS];
    const int b = blockIdx.x, tid = threadIdx.x;
    for (int i = tid; i < NBINS; i += 256)
        offs[i] = binstart[i] + colscanG[i * B1 + b];
    __syncthreads();
    const int e0 = b * EPB;
    for (int e = e0 + tid; e < e0 + EPB; e += 256) {
        const int s = esrc[e], d = edst[e];
        const int p = atomicAdd(&offs[d >> 6], 1);
        sorted[p] = s | ((d & 63) << 17);
    }
}

// ---------------------------------------------------------------------------
// Per-layer: block per bin. LDS-accumulated neighbor sum (4 wave replicas),
// fused node update + per-graph reduction (~1 global atomic per block).
// ---------------------------------------------------------------------------
__global__ __launch_bounds__(256) void binned_scatter_kernel(
    const int* __restrict__ sorted, const int* __restrict__ binstart,
    const float* __restrict__ pin, const float* __restrict__ self_in,
    const float* __restrict__ wself_p, const float* __restrict__ bias_p,
    const float* __restrict__ wnext_p,
    float* __restrict__ h_out, float* __restrict__ p_next,
    const int* __restrict__ gid, float* __restrict__ out, int col)
{
    __shared__ float acc[4][64];
    const int b = blockIdx.x, tid = threadIdx.x;
    ((float*)acc)[tid] = 0.f;
    __syncthreads();

    const int st = binstart[b], en = binstart[b + 1];
    const int w = tid >> 6;
    for (int e = st + tid; e < en; e += 256) {
        const int v = sorted[e];
        atomicAdd(&acc[w][v >> 17], pin[v & SRC_MASK]);
    }
    __syncthreads();

    if (tid < 64) {
        const int n = b * 64 + tid;
        const bool valid = (n < N_NODES);
        float h = 0.f;
        int g = 0;
        if (valid) {
            const float nb = acc[0][tid] + acc[1][tid] + acc[2][tid] + acc[3][tid];
            const float sw = wself_p ? *wself_p : 1.0f;
            const float v = nb + *bias_p + sw * self_in[n];
            h = v > 0.f ? v : 0.f;
            h_out[n] = h;
            if (wnext_p) p_next[n] = h * (*wnext_p);
            g = gid[n];
        }
        const int g0 = __shfl(g, 0);            // lane 0 always valid
        if (__all(!valid || g == g0)) {
            float s = h;
            #pragma unroll
            for (int off = 32; off > 0; off >>= 1) s += __shfl_down(s, off);
            if (tid == 0) atomicAdd(&out[(size_t)g0 * N_COLS + col], s);
        } else if (valid) {
            atomicAdd(&out[(size_t)g * N_COLS + col], h);
        }
    }
}

extern "C" void kernel_launch(void* const* d_in, const int* in_sizes, int n_in,
                              void* d_out, int out_size, void* d_ws, size_t ws_size,
                              hipStream_t stream)
{
    (void)in_sizes; (void)n_in; (void)out_size; (void)ws_size;

    const float* x    = (const float*)d_in[0];
    const int*   esrc = (const int*)d_in[1];
    const int*   edst = (const int*)d_in[2];
    const int*   gid  = (const int*)d_in[3];
    const float* Wn0  = (const float*)d_in[4];
    const float* Ws0  = (const float*)d_in[5];
    const float* b0p  = (const float*)d_in[6];
    const float* Wnr  = (const float*)d_in[7];
    const float* Wsr  = (const float*)d_in[8];
    const float* brp  = (const float*)d_in[9];
    float* out = (float*)d_out;

    // workspace layout (~21.8 MB)
    float* bufP  = (float*)d_ws;
    float* bufP2 = bufP  + N_NODES;
    float* bufS  = bufP2 + N_NODES;
    float* bufH  = bufS  + N_NODES;
    int*   starts   = (int*)(bufH + N_NODES);          // 65
    int*   binstart = starts + (N_GRAPHS + 1);         // NBINS+1
    int*   totalG   = binstart + NBINS + 1;            // NBINS
    int*   histG    = totalG + NBINS;                  // NBINS*B1
    int*   colscanG = histG + (size_t)NBINS * B1;      // NBINS*B1
    int*   sorted   = colscanG + (size_t)NBINS * B1;   // N_EDGES
    float* partial  = (float*)(sorted + N_EDGES);      // 32*64*512

    hipMemsetAsync(d_out, 0, (size_t)N_GRAPHS * N_COLS * sizeof(float), stream);

    find_starts_kernel<<<(N_NODES + 255) / 256, 256, 0, stream>>>(gid, starts);
    dots_kernel<<<1024, 256, 0, stream>>>(x, Wn0, Ws0, bufP, bufS);
    colsum_kernel<<<dim3(CCHUNK, N_GRAPHS), 256, 0, stream>>>(x, starts, partial);
    reduce_partial_kernel<<<N_GRAPHS, 512, 0, stream>>>(partial, out);

    hist_kernel<<<B1, 256, 0, stream>>>(edst, histG);
    colscan_kernel<<<NBINS, 256, 0, stream>>>(histG, colscanG, totalG);
    scan2_kernel<<<1, 256, 0, stream>>>(totalG, binstart);
    reorder_kernel<<<B1, 256, 0, stream>>>(esrc, edst, binstart, colscanG, sorted);

    binned_scatter_kernel<<<NBINS, 256, 0, stream>>>(
        sorted, binstart, bufP, bufS, nullptr, b0p, Wnr + 0, bufH, bufP2, gid, out, 512);
    binned_scatter_kernel<<<NBINS, 256, 0, stream>>>(
        sorted, binstart, bufP2, bufH, Wsr + 0, brp + 0, Wnr + 1, bufH, bufP, gid, out, 513);
    binned_scatter_kernel<<<NBINS, 256, 0, stream>>>(
        sorted, binstart, bufP, bufH, Wsr + 1, brp + 1, Wnr + 2, bufH, bufP2, gid, out, 514);
    binned_scatter_kernel<<<NBINS, 256, 0, stream>>>(
        sorted, binstart, bufP2, bufH, Wsr + 2, brp + 2, nullptr, bufH, nullptr, gid, out, 515);
}

// Round 3
// 508.534 us; speedup vs baseline: 2.0038x; 1.0335x over previous
//
#include <hip/hip_runtime.h>

#define N_NODES  100000
#define N_EDGES  3200000
#define N_FEAT   512
#define N_GRAPHS 64
#define N_COLS   516
#define NBINS    1563            // ceil(N_NODES / 64), 64 nodes per bin
#define B1       256             // histogram column blocks
#define EPB      (N_EDGES / B1)  // 12500 edges per block chunk
#define CHUNK    25              // rows per wave in the fused x pass
#define NWAVES   (N_NODES / CHUNK)  // 4000, exact
#define SRC_MASK 0x1FFFF

// ---------------------------------------------------------------------------
// K1 prep: zero out[], find graph starts, per-block edge histogram.
// grid = B1 x 1024.
// ---------------------------------------------------------------------------
__global__ __launch_bounds__(1024) void prep_kernel(
    const int* __restrict__ edst, const int* __restrict__ gid,
    int* __restrict__ histG, int* __restrict__ starts, float* __restrict__ outz)
{
    __shared__ int lh[NBINS];
    const int b = blockIdx.x, tid = threadIdx.x;
    const int gtid = b * 1024 + tid;

    if (gtid < N_GRAPHS * N_COLS) outz[gtid] = 0.f;
    if (gtid < N_NODES) {
        const int g = gid[gtid];
        const int gp = gtid ? gid[gtid - 1] : -1;
        for (int q = gp + 1; q <= g; ++q) starts[q] = gtid;
        if (gtid == N_NODES - 1)
            for (int q = g + 1; q <= N_GRAPHS; ++q) starts[q] = N_NODES;
    }
    for (int i = tid; i < NBINS; i += 1024) lh[i] = 0;
    __syncthreads();
    const int e0 = b * EPB;
    for (int e = e0 + tid; e < e0 + EPB; e += 1024)
        atomicAdd(&lh[edst[e] >> 6], 1);
    __syncthreads();
    for (int i = tid; i < NBINS; i += 1024) histG[i * B1 + b] = lh[i];
}

// ---------------------------------------------------------------------------
// K2 fused x pass: one read of x computes
//   p0[n]=x.Wn, s0[n]=x.Ws (wave-per-row, shuffle reduce)
//   per-graph colsum partials (registers, flushed to per-wave slots; no atomics)
//   zeroes neigh[]
// Wave w owns rows [25w, 25w+25). Lane l owns cols [8l, 8l+8).
// ---------------------------------------------------------------------------
__device__ __forceinline__ void flush_cs(
    int si, int cur_g, const float a[8], int wave, int lane,
    float* __restrict__ pp, int* __restrict__ pt, float* __restrict__ out)
{
    if (si < 2) {
        const int slot = wave * 2 + si;
        if (lane == 0) pt[slot] = cur_g;
        float* d = pp + (size_t)slot * N_FEAT + lane * 8;
        *(float4*)d       = make_float4(a[0], a[1], a[2], a[3]);
        *(float4*)(d + 4) = make_float4(a[4], a[5], a[6], a[7]);
    } else {
        float* o = out + (size_t)cur_g * N_COLS + lane * 8;
        #pragma unroll
        for (int k = 0; k < 8; ++k) atomicAdd(o + k, a[k]);
    }
}

__global__ __launch_bounds__(256) void pass_x_kernel(
    const float* __restrict__ x, const int* __restrict__ gid,
    const float* __restrict__ wn, const float* __restrict__ ws,
    float* __restrict__ p0, float* __restrict__ s0,
    float* __restrict__ neigh, float* __restrict__ out,
    float* __restrict__ pp, int* __restrict__ pt)
{
    const int wave = (blockIdx.x * blockDim.x + threadIdx.x) >> 6;
    const int lane = threadIdx.x & 63;
    const int start = wave * CHUNK, end = start + CHUNK;   // exact fit

    for (int n = start + lane; n < end; n += 64) neigh[n] = 0.f;

    const float4 wna = *(const float4*)(wn + lane * 8);
    const float4 wnb = *(const float4*)(wn + lane * 8 + 4);
    const float4 wsa = *(const float4*)(ws + lane * 8);
    const float4 wsb = *(const float4*)(ws + lane * 8 + 4);

    float a[8] = {0.f, 0.f, 0.f, 0.f, 0.f, 0.f, 0.f, 0.f};
    int cur_g = gid[start];
    const bool uniform = (gid[end - 1] == cur_g);
    int si = 0;

    for (int n = start; n < end; ++n) {
        if (!uniform) {
            const int g = gid[n];
            if (g != cur_g) {
                flush_cs(si, cur_g, a, wave, lane, pp, pt, out);
                ++si;
                #pragma unroll
                for (int k = 0; k < 8; ++k) a[k] = 0.f;
                cur_g = g;
            }
        }
        const float* row = x + (size_t)n * N_FEAT;
        const float4 xa = *(const float4*)(row + lane * 8);
        const float4 xb = *(const float4*)(row + lane * 8 + 4);

        a[0] += xa.x; a[1] += xa.y; a[2] += xa.z; a[3] += xa.w;
        a[4] += xb.x; a[5] += xb.y; a[6] += xb.z; a[7] += xb.w;

        float dn = xa.x*wna.x + xa.y*wna.y + xa.z*wna.z + xa.w*wna.w
                 + xb.x*wnb.x + xb.y*wnb.y + xb.z*wnb.z + xb.w*wnb.w;
        float dv = xa.x*wsa.x + xa.y*wsa.y + xa.z*wsa.z + xa.w*wsa.w
                 + xb.x*wsb.x + xb.y*wsb.y + xb.z*wsb.z + xb.w*wsb.w;
        #pragma unroll
        for (int off = 32; off > 0; off >>= 1) {
            dn += __shfl_down(dn, off);
            dv += __shfl_down(dv, off);
        }
        if (lane == 0) { p0[n] = dn; s0[n] = dv; }
    }
    flush_cs(si, cur_g, a, wave, lane, pp, pt, out);
    ++si;
    if (lane == 0)
        for (int s2 = si; s2 < 2; ++s2) pt[wave * 2 + s2] = -1;  // unused slots
}

// K6: fold per-wave colsum partials into out (graph g's slots live in a
// contiguous wave range). out already holds zero + rare overflow atomics.
__global__ __launch_bounds__(512) void reduce_x_kernel(
    const float* __restrict__ pp, const int* __restrict__ pt,
    const int* __restrict__ starts, float* __restrict__ out)
{
    const int g = blockIdx.x, c = threadIdx.x;
    const int s = starts[g], e = starts[g + 1];
    float acc = 0.f;
    if (e > s) {
        const int w0 = s / CHUNK, w1 = (e - 1) / CHUNK;
        for (int w = w0; w <= w1; ++w) {
            #pragma unroll
            for (int k = 0; k < 2; ++k) {
                const int slot = w * 2 + k;
                if (pt[slot] == g) acc += pp[(size_t)slot * N_FEAT + c];
            }
        }
    }
    out[(size_t)g * N_COLS + c] += acc;
}

// ---------------------------------------------------------------------------
// Sort pipeline (counting sort by dst bin = dst >> 6).
// ---------------------------------------------------------------------------
__global__ __launch_bounds__(256) void colscan_kernel(
    const int* __restrict__ histG, int* __restrict__ colscanG,
    int* __restrict__ totalG)
{
    __shared__ int sc[256];
    const int bin = blockIdx.x, t = threadIdx.x;
    const int v = histG[bin * B1 + t];
    sc[t] = v;
    __syncthreads();
    for (int off = 1; off < 256; off <<= 1) {
        const int a = (t >= off) ? sc[t - off] : 0;
        __syncthreads();
        sc[t] += a;
        __syncthreads();
    }
    colscanG[bin * B1 + t] = sc[t] - v;
    if (t == 255) totalG[bin] = sc[255];
}

__global__ __launch_bounds__(256) void scan2_kernel(
    const int* __restrict__ totalG, int* __restrict__ binstart)
{
    __shared__ int sc[256];
    const int t = threadIdx.x;
    const int CH = 7;
    int loc[CH];
    int s = 0;
    for (int i = 0; i < CH; ++i) {
        const int bin = t * CH + i;
        const int v = (bin < NBINS) ? totalG[bin] : 0;
        loc[i] = s; s += v;
    }
    const int my = s;
    sc[t] = my;
    __syncthreads();
    for (int off = 1; off < 256; off <<= 1) {
        const int a = (t >= off) ? sc[t - off] : 0;
        __syncthreads();
        sc[t] += a;
        __syncthreads();
    }
    const int texcl = sc[t] - my;
    for (int i = 0; i < CH; ++i) {
        const int bin = t * CH + i;
        if (bin < NBINS) binstart[bin] = texcl + loc[i];
    }
    if (t == 255) binstart[NBINS] = sc[255];
}

__global__ __launch_bounds__(1024) void reorder_kernel(
    const int* __restrict__ esrc, const int* __restrict__ edst,
    const int* __restrict__ binstart, const int* __restrict__ colscanG,
    int* __restrict__ sorted)
{
    __shared__ int offs[NBINS];
    const int b = blockIdx.x, tid = threadIdx.x;
    for (int i = tid; i < NBINS; i += 1024)
        offs[i] = binstart[i] + colscanG[i * B1 + b];
    __syncthreads();
    const int e0 = b * EPB;
    for (int e = e0 + tid; e < e0 + EPB; e += 1024) {
        const int s = esrc[e], d = edst[e];
        const int p = atomicAdd(&offs[d >> 6], 1);
        sorted[p] = s | ((d & 63) << 17);
    }
}

// ---------------------------------------------------------------------------
// Per-layer: block per 64-node bin, LDS-accumulated neighbor sum + fused
// node update + per-graph reduction (~1 global atomic per block).
// ---------------------------------------------------------------------------
__global__ __launch_bounds__(256) void binned_scatter_kernel(
    const int* __restrict__ sorted, const int* __restrict__ binstart,
    const float* __restrict__ pin, const float* __restrict__ self_in,
    const float* __restrict__ wself_p, const float* __restrict__ bias_p,
    const float* __restrict__ wnext_p,
    float* __restrict__ h_out, float* __restrict__ p_next,
    const int* __restrict__ gid, float* __restrict__ out, int col)
{
    __shared__ float acc[4][64];
    const int b = blockIdx.x, tid = threadIdx.x;
    ((float*)acc)[tid] = 0.f;
    __syncthreads();

    const int st = binstart[b], en = binstart[b + 1];
    const int w = tid >> 6;
    for (int e = st + tid; e < en; e += 256) {
        const int v = sorted[e];
        atomicAdd(&acc[w][v >> 17], pin[v & SRC_MASK]);
    }
    __syncthreads();

    if (tid < 64) {
        const int n = b * 64 + tid;
        const bool valid = (n < N_NODES);
        float h = 0.f;
        int g = 0;
        if (valid) {
            const float nb = acc[0][tid] + acc[1][tid] + acc[2][tid] + acc[3][tid];
            const float sw = wself_p ? *wself_p : 1.0f;
            const float v = nb + *bias_p + sw * self_in[n];
            h = v > 0.f ? v : 0.f;
            h_out[n] = h;
            if (wnext_p) p_next[n] = h * (*wnext_p);
            g = gid[n];
        }
        const int g0 = __shfl(g, 0);
        if (__all(!valid || g == g0)) {
            float s = h;
            #pragma unroll
            for (int off = 32; off > 0; off >>= 1) s += __shfl_down(s, off);
            if (tid == 0) atomicAdd(&out[(size_t)g0 * N_COLS + col], s);
        } else if (valid) {
            atomicAdd(&out[(size_t)g * N_COLS + col], h);
        }
    }
}

extern "C" void kernel_launch(void* const* d_in, const int* in_sizes, int n_in,
                              void* d_out, int out_size, void* d_ws, size_t ws_size,
                              hipStream_t stream)
{
    (void)in_sizes; (void)n_in; (void)out_size; (void)ws_size;

    const float* x    = (const float*)d_in[0];
    const int*   esrc = (const int*)d_in[1];
    const int*   edst = (const int*)d_in[2];
    const int*   gid  = (const int*)d_in[3];
    const float* Wn0  = (const float*)d_in[4];
    const float* Ws0  = (const float*)d_in[5];
    const float* b0p  = (const float*)d_in[6];
    const float* Wnr  = (const float*)d_in[7];
    const float* Wsr  = (const float*)d_in[8];
    const float* brp  = (const float*)d_in[9];
    float* out = (float*)d_out;

    // workspace layout (16B-aligned first)
    float* pp    = (float*)d_ws;                         // NWAVES*2*512 floats
    float* bufP  = pp + (size_t)NWAVES * 2 * N_FEAT;
    float* bufP2 = bufP  + N_NODES;
    float* bufS  = bufP2 + N_NODES;
    float* bufH  = bufS  + N_NODES;
    int*   pt       = (int*)(bufH + N_NODES);            // NWAVES*2
    int*   starts   = pt + NWAVES * 2;                   // 65
    int*   binstart = starts + (N_GRAPHS + 1);           // NBINS+1
    int*   totalG   = binstart + NBINS + 1;              // NBINS
    int*   histG    = totalG + NBINS;                    // NBINS*B1
    int*   colscanG = histG + (size_t)NBINS * B1;        // NBINS*B1
    int*   sorted   = colscanG + (size_t)NBINS * B1;     // N_EDGES

    prep_kernel<<<B1, 1024, 0, stream>>>(edst, gid, histG, starts, out);
    pass_x_kernel<<<NWAVES / 4, 256, 0, stream>>>(
        x, gid, Wn0, Ws0, bufP, bufS, bufP2 /*neigh-zero scratch unused*/,
        out, pp, pt);
    // NOTE: neigh zeroing goes into bufP2? NO — layer-0 scatter accumulates in
    // LDS, no global neigh needed. The argument is kept as a dummy.
    colscan_kernel<<<NBINS, 256, 0, stream>>>(histG, colscanG, totalG);
    scan2_kernel<<<1, 256, 0, stream>>>(totalG, binstart);
    reorder_kernel<<<B1, 1024, 0, stream>>>(esrc, edst, binstart, colscanG, sorted);
    reduce_x_kernel<<<N_GRAPHS, 512, 0, stream>>>(pp, pt, starts, out);

    binned_scatter_kernel<<<NBINS, 256, 0, stream>>>(
        sorted, binstart, bufP, bufS, nullptr, b0p, Wnr + 0, bufH, bufP2, gid, out, 512);
    binned_scatter_kernel<<<NBINS, 256, 0, stream>>>(
        sorted, binstart, bufP2, bufH, Wsr + 0, brp + 0, Wnr + 1, bufH, bufP, gid, out, 513);
    binned_scatter_kernel<<<NBINS, 256, 0, stream>>>(
        sorted, binstart, bufP, bufH, Wsr + 1, brp + 1, Wnr + 2, bufH, bufP2, gid, out, 514);
    binned_scatter_kernel<<<NBINS, 256, 0, stream>>>(
        sorted, binstart, bufP2, bufH, Wsr + 2, brp + 2, nullptr, bufH, nullptr, gid, out, 515);
}